// Round 9
// baseline (209.575 us; speedup 1.0000x reference)
//
#include <hip/hip_runtime.h>
#include <hip/hip_bf16.h>
#include <math.h>

// ---------------------------------------------------------------------------
// TaggingQuantizer: cosine-distance VQ assignment + loss + pos/neg reorder.
//   z: (65536, 256) f32,  W: (1024, 256) f32
//   out: emb (1024*256) | label (1024) | loss (1)   all f32, flat-concat.
//
// k_score: 128 tok x 1024 codes. Chunk 0 (256 codes) -> tight bestk with ONE
// barrier; chunks 1-3 stream barrier-free admitting vs monotone stale bestk
// (R5 lesson: admission vs own-chunk max guarantees >=1 admit/wave/chunk ->
// overflow; admission vs a 256-code-tight best admits ~1-3 total).
// Unique survivors finish via the loss identity; ambiguous -> worklist.
// ---------------------------------------------------------------------------

typedef unsigned short u16;
typedef unsigned int   u32;
typedef unsigned long long u64;
typedef __attribute__((ext_vector_type(8))) short short8;  // 8 bf16
typedef __attribute__((ext_vector_type(4))) float f32x4;

#define N_E   1024
#define E_DIM 256
#define N_TOK 65536
#define BETA  0.25f
#define CAPL  20      // LDS slots/token
#define CAPG  8       // global candidates/token
#define D_ADM 0.08f   // admission margin (~14 sigma of pairwise bf16-dot err)
#define D_FIL 0.09f   // final filter: D_ADM + fix16 trunc + margin

// ws layout (bytes)
#define WS_INVNORM 0          // float[1024]
#define WS_NORMW   4096       // float[1024]
#define WS_MASK    8192       // int[1024]
#define WS_LACC    12288      // double[256] -> 14336
#define WS_WCNT    14336      // u32 worklist counter
#define WS_WSW     16384      // u16[1024*256] swizzled bf16 Wn (512 KB)
#define WS_CNT     540672     // u32[65536]
#define WS_CAND    802816     // u16[65536*CAPG] (1 MB)
#define WS_WLIST   1851392    // u32[65536] (256 KB) -> 2107648

static __device__ __forceinline__ u16 f2bf(float f) {   // RNE f32->bf16
    u32 u = __float_as_uint(f);
    return (u16)((u + 0x7FFFu + ((u >> 16) & 1u)) >> 16);
}
static __device__ __forceinline__ u32 pk2bf(float a, float b) { // v_cvt_pk path
    __hip_bfloat162 p = __float22bfloat162_rn(make_float2(a, b));
    return *reinterpret_cast<u32*>(&p);
}
static __device__ __forceinline__ u32 keyenc(float f) { // monotone f32->u32
    u32 u = __float_as_uint(f);
    return u ^ (u32)(((int)u >> 31) | 0x80000000);
}
static __device__ __forceinline__ float keydec(u32 k) {
    u32 u = (k & 0x80000000u) ? (k ^ 0x80000000u) : ~k;
    return __uint_as_float(u);
}

// --------------------------------------------------------------------------
// K1 prep: norms + swizzled bf16 normalized W in MFMA B-fragment order:
// fragment (nb8,kc,nt) at u16 offset ((nb8*8+kc)*8+nt)*512 + lane*8,
// where code n = nb8*128 + nt*16 + col. Zeroes mask/lacc/wcnt.
// --------------------------------------------------------------------------
__global__ void k_prep(const float* __restrict__ W, u16* __restrict__ Wsw,
                       float* __restrict__ inv_norm, float* __restrict__ normW,
                       int* __restrict__ mask, double* __restrict__ lacc,
                       u32* __restrict__ wcnt) {
    const int n = blockIdx.x;      // 1024
    const int l = threadIdx.x;     // 64
    const float4 v = reinterpret_cast<const float4*>(W + (size_t)n * E_DIM)[l];
    float s = v.x * v.x + v.y * v.y + v.z * v.z + v.w * v.w;
#pragma unroll
    for (int sh = 1; sh < 64; sh <<= 1) s += __shfl_xor(s, sh, 64);
    const float nw = sqrtf(s), inv = 1.0f / nw;
    if (l == 0) {
        inv_norm[n] = inv; normW[n] = nw; mask[n] = 0;
        if (n < 256) lacc[n] = 0.0;
        if (n == 0) *wcnt = 0u;
    }
    const int o = l >> 1;          // k-octet 0..31
    const int kc = o >> 2, q = o & 3;
    const size_t base =
        (((((size_t)(n >> 7) * 8 + kc) * 8 + ((n >> 4) & 7)) * 64 +
          (q * 16 + (n & 15))) * 8) + (l & 1) * 4;
    u16* dst = Wsw + base;
    dst[0] = f2bf(v.x * inv);
    dst[1] = f2bf(v.y * inv);
    dst[2] = f2bf(v.z * inv);
    dst[3] = f2bf(v.w * inv);
}

// --------------------------------------------------------------------------
// K2 score: 128 tokens x 1024 codes, 512 threads = 8 waves
// (2 mq x 4 nq, 4x4 acc/wave over 256-code chunks). One barrier after
// chunk 0; chunks 1-3 stream barrier-free.
// LDS: A 64KB + bestk/cnt 1KB + slots 10KB = 75 KB -> 2 blocks/CU.
// --------------------------------------------------------------------------
__global__ __launch_bounds__(512, 4)
void k_score(const float* __restrict__ z, const u16* __restrict__ Wsw,
             const float* __restrict__ normW, u16* __restrict__ cand_g,
             u32* __restrict__ cnt_g, int* __restrict__ mask,
             u32* __restrict__ wlist, u32* __restrict__ wcnt,
             double* __restrict__ lacc) {
    __shared__ __align__(16) u16 A_sw[32768];   // [kc(8)][mt(8)][lane(64)][j(8)]
    __shared__ u32 bestk[128];
    __shared__ u32 cnt[128];
    __shared__ u32 slots[128 * CAPL];           // (fix16 score<<16) | code

    const int t    = threadIdx.x;
    const int lane = t & 63;
    const int w    = t >> 6;
    const size_t tok_base = (size_t)blockIdx.x * 128;

    if (t < 128) { bestk[t] = 0u; cnt[t] = 0u; }

    // ---- staging (coalesced; packed bf16 conversion) + fused sum(z^2) ----
    float ssq = 0.f;
#pragma unroll
    for (int i = 0; i < 8; i++) {
        const int c = t + 512 * i;     // 128 rows x 32 octets
        const int m = c >> 5, o = c & 31;
        const float* zp = z + (tok_base + m) * E_DIM + o * 8;
        const float4 v0 = reinterpret_cast<const float4*>(zp)[0];
        const float4 v1 = reinterpret_cast<const float4*>(zp)[1];
        ssq += v0.x * v0.x + v0.y * v0.y + v0.z * v0.z + v0.w * v0.w
             + v1.x * v1.x + v1.y * v1.y + v1.z * v1.z + v1.w * v1.w;
        uint4 d;
        d.x = pk2bf(v0.x, v0.y);
        d.y = pk2bf(v0.z, v0.w);
        d.z = pk2bf(v1.x, v1.y);
        d.w = pk2bf(v1.z, v1.w);
        const int kc = o >> 2, q = o & 3, col = m & 15, mt = m >> 4;
        *reinterpret_cast<uint4*>(A_sw + ((size_t)((kc * 8 + mt) * 64 + q * 16 + col)) * 8) = d;
    }
#pragma unroll
    for (int sh = 1; sh < 64; sh <<= 1) ssq += __shfl_xor(ssq, sh, 64);
    if (lane == 0) atomicAdd(&lacc[(blockIdx.x * 8 + w) & 255], (double)ssq);
    __syncthreads();

    const int mq = w >> 2;                 // token half (64 tokens, mi=4)
    const int nq = w & 3;                  // code 64-group within chunk (ni=4)
    const int q = lane >> 4, col = lane & 15;
    const u16* wb = Wsw + ((size_t)((nq >> 1) * 64 + (nq & 1) * 4)) * 512
                        + (size_t)lane * 8;

    f32x4 acc[4][4];

#define ZERO_ACC() { _Pragma("unroll") for (int mi = 0; mi < 4; mi++) \
    _Pragma("unroll") for (int ni = 0; ni < 4; ni++) { \
        f32x4 zf = {0.f, 0.f, 0.f, 0.f}; acc[mi][ni] = zf; } }

#define KLOOP(NB2) { \
    _Pragma("unroll 4") \
    for (int kc = 0; kc < 8; kc++) { \
        short8 bf[4], af[4]; \
        _Pragma("unroll") for (int ni = 0; ni < 4; ni++) \
            bf[ni] = *reinterpret_cast<const short8*>( \
                wb + (size_t)((NB2) * 128 + kc * 8 + ni) * 512); \
        _Pragma("unroll") for (int mi = 0; mi < 4; mi++) \
            af[mi] = *reinterpret_cast<const short8*>( \
                A_sw + ((size_t)((kc * 8 + mq * 4 + mi) * 64 + lane)) * 8); \
        _Pragma("unroll") for (int mi = 0; mi < 4; mi++) \
        _Pragma("unroll") for (int ni = 0; ni < 4; ni++) \
            acc[mi][ni] = __builtin_amdgcn_mfma_f32_16x16x32_bf16( \
                af[mi], bf[ni], acc[mi][ni], 0, 0, 0); } }

#define ADMIT(NB2, DO_MAX) { \
    _Pragma("unroll") for (int mi = 0; mi < 4; mi++) \
    _Pragma("unroll") for (int r = 0; r < 4; r++) { \
        const int tk = mq * 64 + mi * 16 + q * 4 + r; \
        const float thr = keydec(bestk[tk]) - D_ADM; \
        _Pragma("unroll") for (int ni = 0; ni < 4; ni++) { \
            const float v = acc[mi][ni][r]; \
            if (v >= thr) { \
                if (DO_MAX) atomicMax(&bestk[tk], keyenc(v)); \
                const int code = ((NB2) * 16 + nq * 4 + ni) * 16 + col; \
                const u32 sl = atomicAdd(&cnt[tk], 1u); \
                if (sl < CAPL) { \
                    const float vc = fminf(fmaxf((v + 16.f) * 2048.f, 0.f), 65535.f); \
                    slots[tk * CAPL + sl] = ((u32)vc << 16) | (u32)code; \
                } } } } }

    // ---- chunk 0: compute, tight bestk (shfl chains + ONE barrier), admit --
    ZERO_ACC();
    KLOOP(0);
#pragma unroll
    for (int mi = 0; mi < 4; mi++)
#pragma unroll
        for (int r = 0; r < 4; r++) {
            float m0 = fmaxf(fmaxf(acc[mi][0][r], acc[mi][1][r]),
                             fmaxf(acc[mi][2][r], acc[mi][3][r]));
#pragma unroll
            for (int sh = 1; sh < 16; sh <<= 1)
                m0 = fmaxf(m0, __shfl_xor(m0, sh, 64));
            if (col == 0)
                atomicMax(&bestk[mq * 64 + mi * 16 + q * 4 + r], keyenc(m0));
        }
    __syncthreads();   // bestk now tight over 256 codes
    ADMIT(0, 0);

    // ---- chunks 1-3: barrier-free streaming; stale bestk only loosens
    // admission (monotone), never drops the true winner ----
#pragma unroll 1
    for (int nb2 = 1; nb2 < 4; nb2++) {
        ZERO_ACC();
        KLOOP(nb2);
        ADMIT(nb2, 1);
    }
#undef ZERO_ACC
#undef KLOOP
#undef ADMIT

    __syncthreads();
    // ---- compaction: unique survivor -> finish here; else -> worklist ----
    if (t < 128) {
        const size_t tokg = tok_base + t;
        const u32 c = cnt[t];
        const float best = keydec(bestk[t]);
        bool amb = false;
        float xacc = 0.f;
        if (c > CAPL) {
            cnt_g[tokg] = 0xFFFFFFFFu; amb = true;      // overflow -> full scan
        } else {
            const float thrf = best - D_FIL;
            u16 loc[CAPG]; u32 m = 0;
            for (u32 i = 0; i < c; i++) {
                const u32 s2 = slots[t * CAPL + i];
                const float ap = (float)(s2 >> 16) * (1.0f / 2048.0f) - 16.0f;
                if (ap >= thrf) { if (m < CAPG) loc[m] = (u16)(s2 & 0xFFFFu); m++; }
            }
            if (m == 1) {
                const int bi = loc[0];
                mask[bi] = 1;                            // benign race
                const float nw = normW[bi];
                xacc = fmaf(-2.0f * best, nw, nw * nw);  // -2 z.Wbi + |Wbi|^2
            } else if (m <= CAPG) {
                for (u32 i = 0; i < m; i++) cand_g[tokg * CAPG + i] = loc[i];
                cnt_g[tokg] = m; amb = true;
            } else {
                cnt_g[tokg] = 0xFFFFFFFFu; amb = true;
            }
        }
        const u64 bal = __ballot(amb);
        u32 base = 0;
        if (lane == 0) base = atomicAdd(wcnt, (u32)__popcll(bal));
        base = (u32)__shfl((int)base, 0, 64);
        if (amb) wlist[base + (u32)__popcll(bal & ((1ull << lane) - 1ull))] = (u32)tokg;
        float xs = xacc;
#pragma unroll
        for (int sh = 1; sh < 64; sh <<= 1) xs += __shfl_xor(xs, sh, 64);
        if (lane == 0) atomicAdd(&lacc[(blockIdx.x * 2 + w) & 255], (double)xs);
    }
}

// --------------------------------------------------------------------------
// K3 pick: worklist-only exact fp32 rescore (16 lanes/token, grid-stride).
// Winner by score (lowest idx on ties); adds exact cross-term; sets mask.
// --------------------------------------------------------------------------
__global__ __launch_bounds__(256)
void k_pick(const float* __restrict__ z, const float* __restrict__ W,
            const float* __restrict__ inv_norm, const float* __restrict__ normW,
            const u16* __restrict__ cand_g, const u32* __restrict__ cnt_g,
            const u32* __restrict__ wlist, const u32* __restrict__ wcnt,
            int* __restrict__ mask, double* __restrict__ lacc) {
    const int t = threadIdx.x, lane = t & 63;
    const int gl = t & 15, grp = t >> 4;
    const u32 total = *wcnt;
    float xs = 0.f;
    for (u32 i = blockIdx.x * 16 + grp; i < total; i += 2048 * 16) {
        const size_t tok = wlist[i];
        float4 zv[4];
#pragma unroll
        for (int j = 0; j < 4; j++)
            zv[j] = reinterpret_cast<const float4*>(z + tok * E_DIM)[j * 16 + gl];
        const u32 sc = cnt_g[tok];
        const bool full = (sc == 0xFFFFFFFFu);
        const int n_it = full ? N_E : (int)sc;
        float bv = -3.4e38f, bp = 0.f;
        int bi = 0x7FFFFFFF;
#pragma unroll 1
        for (int k2 = 0; k2 < n_it; k2++) {
            const int c = full ? k2 : (int)cand_g[tok * CAPG + k2];
            float p = 0.f;
#pragma unroll
            for (int j = 0; j < 4; j++) {
                const float4 wv = reinterpret_cast<const float4*>(W + (size_t)c * E_DIM)[j * 16 + gl];
                p += zv[j].x * wv.x + zv[j].y * wv.y + zv[j].z * wv.z + zv[j].w * wv.w;
            }
#pragma unroll
            for (int sh = 1; sh < 16; sh <<= 1) p += __shfl_xor(p, sh, 64);
            const float s = p * inv_norm[c];
            if (s > bv || (s == bv && c < bi)) { bv = s; bi = c; bp = p; }
        }
        if (gl == 0) {
            mask[bi] = 1;
            xs += fmaf(-2.0f, bp, normW[bi] * normW[bi]);
        }
    }
    xs += __shfl_xor(xs, 16, 64);
    xs += __shfl_xor(xs, 32, 64);
    if (lane == 0) atomicAdd(&lacc[(blockIdx.x * 4 + (t >> 6)) & 255], (double)xs);
}

// --------------------------------------------------------------------------
// K4 emit (fused rank): each block redundantly reduces mask for prefix(e)
// and total; writes emb row + label. Block 0 finalizes loss.
// --------------------------------------------------------------------------
__global__ __launch_bounds__(256)
void k_emit(const float* __restrict__ W, const int* __restrict__ mask,
            const double* __restrict__ lacc, float* __restrict__ out) {
    __shared__ int    redp[256], redt[256];
    __shared__ double dred[256];
    const int e = blockIdx.x;              // 1024
    const int t = threadIdx.x;             // 256
    const int4 mv = reinterpret_cast<const int4*>(mask)[t];
    const int b = t * 4;
    redt[t] = mv.x + mv.y + mv.z + mv.w;
    redp[t] = (b + 0 < e ? mv.x : 0) + (b + 1 < e ? mv.y : 0) +
              (b + 2 < e ? mv.z : 0) + (b + 3 < e ? mv.w : 0);
    if (e == 0) dred[t] = lacc[t];
    __syncthreads();
#pragma unroll
    for (int s2 = 128; s2 > 0; s2 >>= 1) {
        if (t < s2) {
            redp[t] += redp[t + s2];
            redt[t] += redt[t + s2];
            if (e == 0) dred[t] += dred[t + s2];
        }
        __syncthreads();
    }
    const int prefix = redp[0], total = redt[0];
    const int m = mask[e];
    const int r = m ? prefix : (total + e - prefix);
    out[(size_t)r * E_DIM + t] = W[(size_t)e * E_DIM + t];
    if (t == 0) out[(size_t)N_E * E_DIM + r] = m ? 1.0f : 0.0f;
    if (e == 0 && t == 0) {
        const double mse = dred[0] / (double)((size_t)N_TOK * E_DIM);
        out[(size_t)N_E * E_DIM + N_E] = (float)((1.0 + (double)BETA) * mse);
    }
}

// --------------------------------------------------------------------------
extern "C" void kernel_launch(void* const* d_in, const int* in_sizes, int n_in,
                              void* d_out, int out_size, void* d_ws, size_t ws_size,
                              hipStream_t stream) {
    const float* z = (const float*)d_in[0];
    const float* W = (const float*)d_in[1];
    float* out = (float*)d_out;
    char* ws = (char*)d_ws;

    float*  inv_norm = (float*)(ws + WS_INVNORM);
    float*  normW    = (float*)(ws + WS_NORMW);
    int*    mask     = (int*)(ws + WS_MASK);
    double* lacc     = (double*)(ws + WS_LACC);
    u32*    wcnt     = (u32*)(ws + WS_WCNT);
    u16*    Wsw      = (u16*)(ws + WS_WSW);
    u32*    cnt      = (u32*)(ws + WS_CNT);
    u16*    cand     = (u16*)(ws + WS_CAND);
    u32*    wlist    = (u32*)(ws + WS_WLIST);

    k_prep <<<N_E, 64, 0, stream>>>(W, Wsw, inv_norm, normW, mask, lacc, wcnt);
    k_score<<<N_TOK / 128, 512, 0, stream>>>(z, Wsw, normW, cand, cnt, mask,
                                             wlist, wcnt, lacc);
    k_pick <<<2048, 256, 0, stream>>>(z, W, inv_norm, normW, cand, cnt,
                                      wlist, wcnt, mask, lacc);
    k_emit <<<N_E, 256, 0, stream>>>(W, mask, lacc, out);
}

// Round 10
// 152.226 us; speedup vs baseline: 1.3767x; 1.3767x over previous
//
#include <hip/hip_runtime.h>
#include <hip/hip_bf16.h>
#include <math.h>

// ---------------------------------------------------------------------------
// TaggingQuantizer: cosine-distance VQ assignment + loss + pos/neg reorder.
//   z: (65536, 256) f32,  W: (1024, 256) f32
//   out: emb (1024*256) | label (1024) | loss (1)   all f32, flat-concat.
//
// k_score: bf16 MFMA screen, chunk0-tight bestk (one barrier) then
// barrier-free streaming chunks. Unique survivors finish via the loss
// identity. Ambiguous (2..8 cands) -> wlist -> k_pick (group rescore).
// Overflow (rare) -> wlist2 -> k_pick2 (block-parallel full scan; R9's
// 388us serial-fallback pathology eliminated).
// ---------------------------------------------------------------------------

typedef unsigned short u16;
typedef unsigned int   u32;
typedef unsigned long long u64;
typedef __attribute__((ext_vector_type(8))) short short8;  // 8 bf16
typedef __attribute__((ext_vector_type(4))) float f32x4;

#define N_E   1024
#define E_DIM 256
#define N_TOK 65536
#define BETA  0.25f
#define CAPL  24      // LDS slots/token
#define CAPG  8       // global candidates/token
#define D_ADM 0.08f   // admission margin (>=14 sigma of pairwise bf16-dot err)
#define D_FIL 0.09f   // final filter: D_ADM + fix16 trunc + margin

// ws layout (bytes)
#define WS_INVNORM 0          // float[1024]
#define WS_NORMW   4096       // float[1024]
#define WS_MASK    8192       // int[1024]
#define WS_LACC    12288      // double[256] -> 14336
#define WS_WCNT    14336      // u32 worklist counter
#define WS_WCNT2   14340      // u32 overflow-list counter
#define WS_WSW     16384      // u16[1024*256] swizzled bf16 Wn (512 KB)
#define WS_CNT     540672     // u32[65536]
#define WS_CAND    802816     // u16[65536*CAPG] (1 MB) -> 1851392
#define WS_WLIST   1851392    // u32[65536] -> 2113536
#define WS_WLIST2  2113536    // u32[65536] -> 2375680

static __device__ __forceinline__ u16 f2bf(float f) {   // RNE f32->bf16
    u32 u = __float_as_uint(f);
    return (u16)((u + 0x7FFFu + ((u >> 16) & 1u)) >> 16);
}
static __device__ __forceinline__ u32 pk2bf(float a, float b) { // v_cvt_pk path
    __hip_bfloat162 p = __float22bfloat162_rn(make_float2(a, b));
    return *reinterpret_cast<u32*>(&p);
}
static __device__ __forceinline__ u32 keyenc(float f) { // monotone f32->u32
    u32 u = __float_as_uint(f);
    return u ^ (u32)(((int)u >> 31) | 0x80000000);
}
static __device__ __forceinline__ float keydec(u32 k) {
    u32 u = (k & 0x80000000u) ? (k ^ 0x80000000u) : ~k;
    return __uint_as_float(u);
}

// --------------------------------------------------------------------------
// K1 prep: norms + swizzled bf16 normalized W in MFMA B-fragment order.
// Zeroes mask/lacc/wcnt/wcnt2 (ws re-poisoned each call).
// --------------------------------------------------------------------------
__global__ void k_prep(const float* __restrict__ W, u16* __restrict__ Wsw,
                       float* __restrict__ inv_norm, float* __restrict__ normW,
                       int* __restrict__ mask, double* __restrict__ lacc,
                       u32* __restrict__ wcnt, u32* __restrict__ wcnt2) {
    const int n = blockIdx.x;      // 1024
    const int l = threadIdx.x;     // 64
    const float4 v = reinterpret_cast<const float4*>(W + (size_t)n * E_DIM)[l];
    float s = v.x * v.x + v.y * v.y + v.z * v.z + v.w * v.w;
#pragma unroll
    for (int sh = 1; sh < 64; sh <<= 1) s += __shfl_xor(s, sh, 64);
    const float nw = sqrtf(s), inv = 1.0f / nw;
    if (l == 0) {
        inv_norm[n] = inv; normW[n] = nw; mask[n] = 0;
        if (n < 256) lacc[n] = 0.0;
        if (n == 0) { *wcnt = 0u; *wcnt2 = 0u; }
    }
    const int o = l >> 1;          // k-octet 0..31
    const int kc = o >> 2, q = o & 3;
    const size_t base =
        (((((size_t)(n >> 7) * 8 + kc) * 8 + ((n >> 4) & 7)) * 64 +
          (q * 16 + (n & 15))) * 8) + (l & 1) * 4;
    u16* dst = Wsw + base;
    dst[0] = f2bf(v.x * inv);
    dst[1] = f2bf(v.y * inv);
    dst[2] = f2bf(v.z * inv);
    dst[3] = f2bf(v.w * inv);
}

// --------------------------------------------------------------------------
// K2 score: 128 tokens x 1024 codes, 512 threads = 8 waves
// (2 mq x 4 nq, 4x4 acc/wave over 256-code chunks). One barrier after
// chunk 0 (tight bestk); chunks 1-3 stream barrier-free.
// LDS: A 64KB + bestk/cnt 1KB + slots 12KB = 78.8 KB -> 2 blocks/CU.
// --------------------------------------------------------------------------
__global__ __launch_bounds__(512, 4)
void k_score(const float* __restrict__ z, const u16* __restrict__ Wsw,
             const float* __restrict__ normW, u16* __restrict__ cand_g,
             u32* __restrict__ cnt_g, int* __restrict__ mask,
             u32* __restrict__ wlist, u32* __restrict__ wcnt,
             u32* __restrict__ wlist2, u32* __restrict__ wcnt2,
             double* __restrict__ lacc) {
    __shared__ __align__(16) u16 A_sw[32768];   // [kc(8)][mt(8)][lane(64)][j(8)]
    __shared__ u32 bestk[128];
    __shared__ u32 cnt[128];
    __shared__ u32 slots[128 * CAPL];           // (fix16 score<<16) | code

    const int t    = threadIdx.x;
    const int lane = t & 63;
    const int w    = t >> 6;
    const size_t tok_base = (size_t)blockIdx.x * 128;

    if (t < 128) { bestk[t] = 0u; cnt[t] = 0u; }

    // ---- staging (coalesced; packed bf16 conversion) + fused sum(z^2) ----
    float ssq = 0.f;
#pragma unroll
    for (int i = 0; i < 8; i++) {
        const int c = t + 512 * i;     // 128 rows x 32 octets
        const int m = c >> 5, o = c & 31;
        const float* zp = z + (tok_base + m) * E_DIM + o * 8;
        const float4 v0 = reinterpret_cast<const float4*>(zp)[0];
        const float4 v1 = reinterpret_cast<const float4*>(zp)[1];
        ssq += v0.x * v0.x + v0.y * v0.y + v0.z * v0.z + v0.w * v0.w
             + v1.x * v1.x + v1.y * v1.y + v1.z * v1.z + v1.w * v1.w;
        uint4 d;
        d.x = pk2bf(v0.x, v0.y);
        d.y = pk2bf(v0.z, v0.w);
        d.z = pk2bf(v1.x, v1.y);
        d.w = pk2bf(v1.z, v1.w);
        const int kc = o >> 2, q = o & 3, col = m & 15, mt = m >> 4;
        *reinterpret_cast<uint4*>(A_sw + ((size_t)((kc * 8 + mt) * 64 + q * 16 + col)) * 8) = d;
    }
#pragma unroll
    for (int sh = 1; sh < 64; sh <<= 1) ssq += __shfl_xor(ssq, sh, 64);
    if (lane == 0) atomicAdd(&lacc[(blockIdx.x * 8 + w) & 255], (double)ssq);
    __syncthreads();

    const int mq = w >> 2;                 // token half (64 tokens, mi=4)
    const int nq = w & 3;                  // code 64-group within chunk (ni=4)
    const int q = lane >> 4, col = lane & 15;
    const u16* wb = Wsw + ((size_t)((nq >> 1) * 64 + (nq & 1) * 4)) * 512
                        + (size_t)lane * 8;

    f32x4 acc[4][4];

#define ZERO_ACC() { _Pragma("unroll") for (int mi = 0; mi < 4; mi++) \
    _Pragma("unroll") for (int ni = 0; ni < 4; ni++) { \
        f32x4 zf = {0.f, 0.f, 0.f, 0.f}; acc[mi][ni] = zf; } }

#define KLOOP(NB2) { \
    _Pragma("unroll 4") \
    for (int kc = 0; kc < 8; kc++) { \
        short8 bf[4], af[4]; \
        _Pragma("unroll") for (int ni = 0; ni < 4; ni++) \
            bf[ni] = *reinterpret_cast<const short8*>( \
                wb + (size_t)((NB2) * 128 + kc * 8 + ni) * 512); \
        _Pragma("unroll") for (int mi = 0; mi < 4; mi++) \
            af[mi] = *reinterpret_cast<const short8*>( \
                A_sw + ((size_t)((kc * 8 + mq * 4 + mi) * 64 + lane)) * 8); \
        _Pragma("unroll") for (int mi = 0; mi < 4; mi++) \
        _Pragma("unroll") for (int ni = 0; ni < 4; ni++) \
            acc[mi][ni] = __builtin_amdgcn_mfma_f32_16x16x32_bf16( \
                af[mi], bf[ni], acc[mi][ni], 0, 0, 0); } }

#define ADMIT(NB2, DO_MAX) { \
    _Pragma("unroll") for (int mi = 0; mi < 4; mi++) \
    _Pragma("unroll") for (int r = 0; r < 4; r++) { \
        const int tk = mq * 64 + mi * 16 + q * 4 + r; \
        const float thr = keydec(bestk[tk]) - D_ADM; \
        _Pragma("unroll") for (int ni = 0; ni < 4; ni++) { \
            const float v = acc[mi][ni][r]; \
            if (v >= thr) { \
                if (DO_MAX) atomicMax(&bestk[tk], keyenc(v)); \
                const int code = ((NB2) * 16 + nq * 4 + ni) * 16 + col; \
                const u32 sl = atomicAdd(&cnt[tk], 1u); \
                if (sl < CAPL) { \
                    const float vc = fminf(fmaxf((v + 16.f) * 2048.f, 0.f), 65535.f); \
                    slots[tk * CAPL + sl] = ((u32)vc << 16) | (u32)code; \
                } } } } }

    // ---- chunk 0: compute, tight bestk (shfl chains + ONE barrier), admit --
    ZERO_ACC();
    KLOOP(0);
#pragma unroll
    for (int mi = 0; mi < 4; mi++)
#pragma unroll
        for (int r = 0; r < 4; r++) {
            float m0 = fmaxf(fmaxf(acc[mi][0][r], acc[mi][1][r]),
                             fmaxf(acc[mi][2][r], acc[mi][3][r]));
#pragma unroll
            for (int sh = 1; sh < 16; sh <<= 1)
                m0 = fmaxf(m0, __shfl_xor(m0, sh, 64));
            if (col == 0)
                atomicMax(&bestk[mq * 64 + mi * 16 + q * 4 + r], keyenc(m0));
        }
    __syncthreads();   // bestk now tight over 256 codes
    ADMIT(0, 0);

    // ---- chunks 1-3: barrier-free streaming (stale bestk only loosens
    // admission; the true winner always passes) ----
#pragma unroll 1
    for (int nb2 = 1; nb2 < 4; nb2++) {
        ZERO_ACC();
        KLOOP(nb2);
        ADMIT(nb2, 1);
    }
#undef ZERO_ACC
#undef KLOOP
#undef ADMIT

    __syncthreads();
    // ---- compaction: m==1 -> finish; 2..CAPG -> wlist; else -> wlist2 ----
    if (t < 128) {
        const size_t tokg = tok_base + t;
        const u32 c = cnt[t];
        const float best = keydec(bestk[t]);
        bool amb = false, ovf = false;
        float xacc = 0.f;
        if (c > CAPL) {
            ovf = true;                                  // rare: full scan
        } else {
            const float thrf = best - D_FIL;
            u16 loc[CAPG]; u32 m = 0;
            for (u32 i = 0; i < c; i++) {
                const u32 s2 = slots[t * CAPL + i];
                const float ap = (float)(s2 >> 16) * (1.0f / 2048.0f) - 16.0f;
                if (ap >= thrf) { if (m < CAPG) loc[m] = (u16)(s2 & 0xFFFFu); m++; }
            }
            if (m == 1) {
                const int bi = loc[0];
                mask[bi] = 1;                            // benign race
                const float nw = normW[bi];
                xacc = fmaf(-2.0f * best, nw, nw * nw);  // -2 z.Wbi + |Wbi|^2
            } else if (m <= CAPG) {
                for (u32 i = 0; i < m; i++) cand_g[tokg * CAPG + i] = loc[i];
                cnt_g[tokg] = m; amb = true;
            } else {
                ovf = true;
            }
        }
        // ambiguous -> wlist
        {
            const u64 bal = __ballot(amb);
            u32 base = 0;
            if (lane == 0 && bal) base = atomicAdd(wcnt, (u32)__popcll(bal));
            base = (u32)__shfl((int)base, 0, 64);
            if (amb) wlist[base + (u32)__popcll(bal & ((1ull << lane) - 1ull))] = (u32)tokg;
        }
        // overflow -> wlist2
        {
            const u64 bal = __ballot(ovf);
            u32 base = 0;
            if (lane == 0 && bal) base = atomicAdd(wcnt2, (u32)__popcll(bal));
            base = (u32)__shfl((int)base, 0, 64);
            if (ovf) wlist2[base + (u32)__popcll(bal & ((1ull << lane) - 1ull))] = (u32)tokg;
        }
        float xs = xacc;
#pragma unroll
        for (int sh = 1; sh < 64; sh <<= 1) xs += __shfl_xor(xs, sh, 64);
        if (lane == 0) atomicAdd(&lacc[(blockIdx.x * 2 + w) & 255], (double)xs);
    }
}

// --------------------------------------------------------------------------
// K3 pick: wlist tokens only (sc in [2,CAPG]). 16 lanes/token, grid-stride.
// Winner by fp32 score (lowest idx on ties); exact cross-term; sets mask.
// --------------------------------------------------------------------------
__global__ __launch_bounds__(256)
void k_pick(const float* __restrict__ z, const float* __restrict__ W,
            const float* __restrict__ inv_norm, const float* __restrict__ normW,
            const u16* __restrict__ cand_g, const u32* __restrict__ cnt_g,
            const u32* __restrict__ wlist, const u32* __restrict__ wcnt,
            int* __restrict__ mask, double* __restrict__ lacc) {
    const int t = threadIdx.x, lane = t & 63;
    const int gl = t & 15, grp = t >> 4;
    const u32 total = *wcnt;
    float xs = 0.f;
    for (u32 i = blockIdx.x * 16 + grp; i < total; i += 1024 * 16) {
        const size_t tok = wlist[i];
        float4 zv[4];
#pragma unroll
        for (int j = 0; j < 4; j++)
            zv[j] = reinterpret_cast<const float4*>(z + tok * E_DIM)[j * 16 + gl];
        const int n_it = (int)cnt_g[tok];
        float bv = -3.4e38f, bp = 0.f;
        int bi = 0x7FFFFFFF;
#pragma unroll 1
        for (int k2 = 0; k2 < n_it; k2++) {
            const int c = (int)cand_g[tok * CAPG + k2];
            float p = 0.f;
#pragma unroll
            for (int j = 0; j < 4; j++) {
                const float4 wv = reinterpret_cast<const float4*>(W + (size_t)c * E_DIM)[j * 16 + gl];
                p += zv[j].x * wv.x + zv[j].y * wv.y + zv[j].z * wv.z + zv[j].w * wv.w;
            }
#pragma unroll
            for (int sh = 1; sh < 16; sh <<= 1) p += __shfl_xor(p, sh, 64);
            const float s = p * inv_norm[c];
            if (s > bv || (s == bv && c < bi)) { bv = s; bi = c; bp = p; }
        }
        if (gl == 0) {
            mask[bi] = 1;
            xs += fmaf(-2.0f, bp, normW[bi] * normW[bi]);
        }
    }
    xs += __shfl_xor(xs, 16, 64);
    xs += __shfl_xor(xs, 32, 64);
    if (lane == 0) atomicAdd(&lacc[(blockIdx.x * 4 + (t >> 6)) & 255], (double)xs);
}

// --------------------------------------------------------------------------
// K3b pick2: overflow tokens — block-parallel exact full scan. 16 groups x
// 64 codes each (2 codes in flight), LDS merge with ascending-index ties.
// --------------------------------------------------------------------------
__global__ __launch_bounds__(256)
void k_pick2(const float* __restrict__ z, const float* __restrict__ W,
             const float* __restrict__ inv_norm, const float* __restrict__ normW,
             const u32* __restrict__ wlist2, const u32* __restrict__ wcnt2,
             int* __restrict__ mask, double* __restrict__ lacc) {
    __shared__ float zrow[E_DIM];
    __shared__ float gbv[16], gbp[16];
    __shared__ int   gbi[16];
    const int t = threadIdx.x;
    const int gl = t & 15, grp = t >> 4;
    const u32 total = *wcnt2;
    for (u32 i = blockIdx.x; i < total; i += 64) {
        const size_t tok = wlist2[i];
        __syncthreads();              // protect zrow reuse across iterations
        zrow[t] = z[tok * E_DIM + t];
        __syncthreads();
        float4 zv[4];
#pragma unroll
        for (int j = 0; j < 4; j++)
            zv[j] = reinterpret_cast<const float4*>(zrow)[j * 16 + gl];
        float bv = -3.4e38f, bp = 0.f;
        int bi = 0x7FFFFFFF;
#pragma unroll 1
        for (int k2 = 0; k2 < 64; k2 += 2) {
            const int c0 = grp * 64 + k2, c1 = c0 + 1;
            float p0 = 0.f, p1 = 0.f;
#pragma unroll
            for (int j = 0; j < 4; j++) {
                const float4 w0 = reinterpret_cast<const float4*>(W + (size_t)c0 * E_DIM)[j * 16 + gl];
                const float4 w1 = reinterpret_cast<const float4*>(W + (size_t)c1 * E_DIM)[j * 16 + gl];
                p0 += zv[j].x * w0.x + zv[j].y * w0.y + zv[j].z * w0.z + zv[j].w * w0.w;
                p1 += zv[j].x * w1.x + zv[j].y * w1.y + zv[j].z * w1.z + zv[j].w * w1.w;
            }
#pragma unroll
            for (int sh = 1; sh < 16; sh <<= 1) {
                p0 += __shfl_xor(p0, sh, 64);
                p1 += __shfl_xor(p1, sh, 64);
            }
            const float s0 = p0 * inv_norm[c0];
            const float s1 = p1 * inv_norm[c1];
            if (s0 > bv || (s0 == bv && c0 < bi)) { bv = s0; bi = c0; bp = p0; }
            if (s1 > bv || (s1 == bv && c1 < bi)) { bv = s1; bi = c1; bp = p1; }
        }
        if (gl == 0) { gbv[grp] = bv; gbi[grp] = bi; gbp[grp] = bp; }
        __syncthreads();
        if (t == 0) {
            float fb = gbv[0], fp = gbp[0];
            int fi = gbi[0];
            for (int g2 = 1; g2 < 16; g2++) {
                const float v2 = gbv[g2];
                const int i2 = gbi[g2];
                if (v2 > fb || (v2 == fb && i2 < fi)) { fb = v2; fi = i2; fp = gbp[g2]; }
            }
            mask[fi] = 1;
            atomicAdd(&lacc[tok & 255],
                      (double)fmaf(-2.0f, fp, normW[fi] * normW[fi]));
        }
    }
}

// --------------------------------------------------------------------------
// K4 emit (fused rank): each block redundantly reduces mask for prefix(e)
// and total; writes emb row + label. Block 0 finalizes loss.
// --------------------------------------------------------------------------
__global__ __launch_bounds__(256)
void k_emit(const float* __restrict__ W, const int* __restrict__ mask,
            const double* __restrict__ lacc, float* __restrict__ out) {
    __shared__ int    redp[256], redt[256];
    __shared__ double dred[256];
    const int e = blockIdx.x;              // 1024
    const int t = threadIdx.x;             // 256
    const int4 mv = reinterpret_cast<const int4*>(mask)[t];
    const int b = t * 4;
    redt[t] = mv.x + mv.y + mv.z + mv.w;
    redp[t] = (b + 0 < e ? mv.x : 0) + (b + 1 < e ? mv.y : 0) +
              (b + 2 < e ? mv.z : 0) + (b + 3 < e ? mv.w : 0);
    if (e == 0) dred[t] = lacc[t];
    __syncthreads();
#pragma unroll
    for (int s2 = 128; s2 > 0; s2 >>= 1) {
        if (t < s2) {
            redp[t] += redp[t + s2];
            redt[t] += redt[t + s2];
            if (e == 0) dred[t] += dred[t + s2];
        }
        __syncthreads();
    }
    const int prefix = redp[0], total = redt[0];
    const int m = mask[e];
    const int r = m ? prefix : (total + e - prefix);
    out[(size_t)r * E_DIM + t] = W[(size_t)e * E_DIM + t];
    if (t == 0) out[(size_t)N_E * E_DIM + r] = m ? 1.0f : 0.0f;
    if (e == 0 && t == 0) {
        const double mse = dred[0] / (double)((size_t)N_TOK * E_DIM);
        out[(size_t)N_E * E_DIM + N_E] = (float)((1.0 + (double)BETA) * mse);
    }
}

// --------------------------------------------------------------------------
extern "C" void kernel_launch(void* const* d_in, const int* in_sizes, int n_in,
                              void* d_out, int out_size, void* d_ws, size_t ws_size,
                              hipStream_t stream) {
    const float* z = (const float*)d_in[0];
    const float* W = (const float*)d_in[1];
    float* out = (float*)d_out;
    char* ws = (char*)d_ws;

    float*  inv_norm = (float*)(ws + WS_INVNORM);
    float*  normW    = (float*)(ws + WS_NORMW);
    int*    mask     = (int*)(ws + WS_MASK);
    double* lacc     = (double*)(ws + WS_LACC);
    u32*    wcnt     = (u32*)(ws + WS_WCNT);
    u32*    wcnt2    = (u32*)(ws + WS_WCNT2);
    u16*    Wsw      = (u16*)(ws + WS_WSW);
    u32*    cnt      = (u32*)(ws + WS_CNT);
    u16*    cand     = (u16*)(ws + WS_CAND);
    u32*    wlist    = (u32*)(ws + WS_WLIST);
    u32*    wlist2   = (u32*)(ws + WS_WLIST2);

    k_prep <<<N_E, 64, 0, stream>>>(W, Wsw, inv_norm, normW, mask, lacc,
                                    wcnt, wcnt2);
    k_score<<<N_TOK / 128, 512, 0, stream>>>(z, Wsw, normW, cand, cnt, mask,
                                             wlist, wcnt, wlist2, wcnt2, lacc);
    k_pick <<<1024, 256, 0, stream>>>(z, W, inv_norm, normW, cand, cnt,
                                      wlist, wcnt, mask, lacc);
    k_pick2<<<64, 256, 0, stream>>>(z, W, inv_norm, normW,
                                    wlist2, wcnt2, mask, lacc);
    k_emit <<<N_E, 256, 0, stream>>>(W, mask, lacc, out);
}